// Round 6
// baseline (204.962 us; speedup 1.0000x reference)
//
#include <hip/hip_runtime.h>
#include <math.h>

#define N 2304
#define D 256
#define K_NB 289
#define NH 8
#define HD 32
#define KS 8            // key segments in attention
#define SEG (N / KS)    // 288
#define NGR 2320        // guarded key count (2304 + 8 each side)

typedef __attribute__((ext_vector_type(8))) short short8;   // 8 bf16
typedef __attribute__((ext_vector_type(4))) short bf16x4;   // 4 bf16
typedef __attribute__((ext_vector_type(4))) float floatx4;  // 4 fp32 (MFMA C/D)

static __device__ __forceinline__ unsigned short f2bf(float x) {
  union { float f; unsigned u; } v; v.f = x;
  unsigned r = (v.u + 0x7fffu + ((v.u >> 16) & 1u)) >> 16;   // RNE
  return (unsigned short)r;
}
static __device__ __forceinline__ unsigned pack2bf(float lo, float hi) {
  return (unsigned)f2bf(lo) | ((unsigned)f2bf(hi) << 16);
}

// ---------------- Prep: x2 fp32 -> bf16 row-major + transposed, zero guards --
__global__ __launch_bounds__(256) void prep_kernel(
    const float* __restrict__ x2, unsigned short* __restrict__ x2b_full,
    unsigned short* __restrict__ x2t_full)
{
  __shared__ unsigned short T[16][17];
  const int tx = threadIdx.x & 15;
  const int ty = threadIdx.x >> 4;
  const int k0 = blockIdx.x * 16;
  const int f0 = blockIdx.y * 16;
  const int key = k0 + ty - 8;
  unsigned short v = 0;
  if (key >= 0 && key < N) v = f2bf(x2[(size_t)key * D + f0 + tx]);
  x2b_full[(size_t)(k0 + ty) * D + f0 + tx] = v;
  T[ty][tx] = v;
  __syncthreads();
  x2t_full[(size_t)(f0 + ty) * NGR + k0 + tx] = T[tx][ty];
}

// ---------------- Stage 1: MFMA window attention + layernorm -----------------
__global__ __launch_bounds__(256) void stage1_mfma_kernel(
    const unsigned short* __restrict__ x2b,
    const unsigned short* __restrict__ x2t,
    const float* __restrict__ gamma, const float* __restrict__ beta,
    float* __restrict__ x2f)
{
  __shared__ float S[16][548];
  __shared__ __align__(16) unsigned short Pb[16][552];
  __shared__ float dinv[16];
  __shared__ float lr1[4][16], lr2[4][16];

  const int t    = threadIdx.x;
  const int w    = t >> 6;
  const int lane = t & 63;
  const int g    = lane >> 4;
  const int cL   = lane & 15;
  const int b  = blockIdx.x;
  const int r  = b / 3;
  const int c0 = (b % 3) * 16;
  const int qbase = r * 48 + c0;
  const int row_lo = max(0, 8 - r);
  const int row_hi = min(16, 55 - r);

  short8 qf[8];
  {
    const unsigned short* qptr = x2b + (size_t)(qbase + cL) * D + g * 8;
    #pragma unroll
    for (int s = 0; s < 8; ++s) qf[s] = *(const short8*)(qptr + s * 32);
  }

  for (int wr = row_lo + w; wr <= row_hi; wr += 4) {
    const int kr = r - 8 + wr;
    const int keybase = kr * 48 + c0 - 8;
    #pragma unroll
    for (int ch = 0; ch < 2; ++ch) {
      const unsigned short* kptr = x2b + (size_t)(keybase + ch * 16 + cL) * D + g * 8;
      floatx4 sa = {0.f, 0.f, 0.f, 0.f};
      #pragma unroll
      for (int s = 0; s < 8; ++s) {
        const short8 kf = *(const short8*)(kptr + s * 32);
        sa = __builtin_amdgcn_mfma_f32_16x16x32_bf16(qf[s], kf, sa, 0, 0, 0);
      }
      #pragma unroll
      for (int reg = 0; reg < 4; ++reg)
        S[g * 4 + reg][wr * 32 + ch * 16 + cL] = sa[reg] * 0.0625f;
    }
  }
  __syncthreads();

  if (t < 16) {
    const int c = c0 + t;
    const int nrows = min(r + 8, 47) - max(r - 8, 0) + 1;
    const int ncols = min(c + 8, 47) - max(c - 8, 0) + 1;
    const int mult  = K_NB - nrows * ncols + 1;
    if (mult > 1) {
      const int wr0 = max(0, 8 - r);
      const int wc0 = (c >= 8) ? t : (8 - c0);
      S[t][wr0 * 32 + wc0] += __logf((float)mult);
    }
  }
  __syncthreads();

  {
    const int qi = t >> 4, ti = t & 15;
    float ssum = 0.f;
    for (int wk = ti; wk < 544; wk += 16) {
      const int wr = wk >> 5, wc = wk & 31;
      const int kr = r - 8 + wr;
      const int kc = c0 - 8 + wc;
      const bool valid = (kr >= 0) & (kr < 48) & (kc >= 0) & (kc < 48) &
                         (wc >= qi) & (wc <= qi + 16);
      const float p = valid ? __expf(S[qi][wk]) : 0.f;
      ssum += p;
      Pb[qi][wk] = valid ? f2bf(p) : (unsigned short)0;
    }
    #pragma unroll
    for (int off = 1; off <= 8; off <<= 1) ssum += __shfl_xor(ssum, off);
    if (ti == 0) dinv[qi] = 1.f / ssum;
  }
  __syncthreads();

  floatx4 acc[4];
  #pragma unroll
  for (int ng = 0; ng < 4; ++ng) acc[ng] = (floatx4){0.f, 0.f, 0.f, 0.f};
  const int fb = w * 64;
  for (int wr = row_lo; wr <= row_hi; ++wr) {
    const int keybase = (r - 8 + wr) * 48 + c0 - 8;
    const short8 pA = *(const short8*)&Pb[cL][wr * 32 + g * 8];
    #pragma unroll
    for (int ng = 0; ng < 4; ++ng) {
      const short8 vf = *(const short8*)(x2t + (size_t)(fb + ng * 16 + cL) * NGR + keybase + g * 8);
      acc[ng] = __builtin_amdgcn_mfma_f32_16x16x32_bf16(pA, vf, acc[ng], 0, 0, 0);
    }
  }

  float vout[4][4], ps1[4] = {0,0,0,0}, ps2[4] = {0,0,0,0};
  #pragma unroll
  for (int reg = 0; reg < 4; ++reg) {
    const float di = dinv[g * 4 + reg];
    #pragma unroll
    for (int ng = 0; ng < 4; ++ng) {
      const float v = acc[ng][reg] * di;
      vout[ng][reg] = v;
      ps1[reg] += v;
      ps2[reg] += v * v;
    }
  }
  #pragma unroll
  for (int off = 1; off <= 8; off <<= 1) {
    #pragma unroll
    for (int reg = 0; reg < 4; ++reg) {
      ps1[reg] += __shfl_xor(ps1[reg], off);
      ps2[reg] += __shfl_xor(ps2[reg], off);
    }
  }
  if (cL == 0) {
    #pragma unroll
    for (int reg = 0; reg < 4; ++reg) {
      lr1[w][g * 4 + reg] = ps1[reg];
      lr2[w][g * 4 + reg] = ps2[reg];
    }
  }
  __syncthreads();
  #pragma unroll
  for (int reg = 0; reg < 4; ++reg) {
    const int m = g * 4 + reg;
    const float s1 = lr1[0][m] + lr1[1][m] + lr1[2][m] + lr1[3][m];
    const float s2 = lr2[0][m] + lr2[1][m] + lr2[2][m] + lr2[3][m];
    const float mu  = s1 * (1.f / 256.f);
    const float var = s2 * (1.f / 256.f) - mu * mu;
    const float rs  = rsqrtf(var + 1e-5f);
    #pragma unroll
    for (int ng = 0; ng < 4; ++ng) {
      const int f = fb + ng * 16 + cL;
      x2f[(size_t)(qbase + m) * D + f] = (vout[ng][reg] - mu) * rs * gamma[f] + beta[f];
    }
  }
}

// ---------------- QKV projection (fp32 core, bf16 epilogue) ------------------
__global__ __launch_bounds__(256) void gemm_qkv_kernel(
    const float* __restrict__ A0, const float* __restrict__ A1,
    const float* __restrict__ W, const float* __restrict__ bias,
    unsigned short* __restrict__ Qb, unsigned short* __restrict__ Kb,
    unsigned short* __restrict__ Vtb)
{
  __shared__ float As[64][68];
  __shared__ float Ws[64][68];
  const int t  = threadIdx.x;
  const int tx = t & 15;
  const int ty = t >> 4;
  const int j0 = blockIdx.x * 64;
  const int m0 = blockIdx.y * 64;
  const float* __restrict__ Asrc = (j0 < 256) ? A0 : A1;

  float acc[4][4];
  #pragma unroll
  for (int r = 0; r < 4; ++r)
    #pragma unroll
    for (int c = 0; c < 4; ++c) acc[r][c] = 0.f;

  for (int kc = 0; kc < D; kc += 64) {
    const int col = tx * 4;
    #pragma unroll
    for (int i = 0; i < 4; ++i) {
      const int r = ty + 16 * i;
      *(float4*)&As[r][col] = *(const float4*)(Asrc + (size_t)(m0 + r) * D + kc + col);
      *(float4*)&Ws[r][col] = *(const float4*)(W    + (size_t)(j0 + r) * D + kc + col);
    }
    __syncthreads();
    #pragma unroll 4
    for (int kk = 0; kk < 64; kk += 4) {
      float4 a4[4], b4[4];
      #pragma unroll
      for (int r = 0; r < 4; ++r) a4[r] = *(const float4*)&As[ty * 4 + r][kk];
      #pragma unroll
      for (int c = 0; c < 4; ++c) b4[c] = *(const float4*)&Ws[tx + 16 * c][kk];
      #pragma unroll
      for (int r = 0; r < 4; ++r)
        #pragma unroll
        for (int c = 0; c < 4; ++c) {
          acc[r][c] += a4[r].x * b4[c].x;
          acc[r][c] += a4[r].y * b4[c].y;
          acc[r][c] += a4[r].z * b4[c].z;
          acc[r][c] += a4[r].w * b4[c].w;
        }
    }
    __syncthreads();
  }
  const float qscale = 0.17677669529663687f;
  #pragma unroll
  for (int r = 0; r < 4; ++r) {
    const int m = m0 + ty * 4 + r;
    #pragma unroll
    for (int c = 0; c < 4; ++c) {
      const int j = j0 + tx + 16 * c;
      const float v = acc[r][c] + bias[j];
      if (j0 < 256)       Qb[(size_t)m * D + j] = f2bf(v * qscale);
      else if (j0 < 512)  Kb[(size_t)m * D + (j - 256)] = f2bf(v);
      else                Vtb[(size_t)(j - 512) * N + m] = f2bf(v);
    }
  }
}

// ---------------- MFMA flash attention: transpose-free -----------------------
// S^T = K·Q^T (16x16x32): lane(g,c) reg r = S^T[key 4g+r][query c].  This IS
// the B-operand layout of mfma_f32_16x16x16bf16_1k (B[k=quad*4+j][n=lane&15]),
// so exp'd probs feed PV directly: O^T = V^T·P^T with A = V^T fragment
// (lane(g,c) holds Vt[feat c][keys 4g..4g+3], an 8B load). No LDS, no DS ops.
__global__ __launch_bounds__(256) void attn_mfma_kernel(
    const unsigned short* __restrict__ Qb, const unsigned short* __restrict__ Kb,
    const unsigned short* __restrict__ Vtb,
    float* __restrict__ pacc, float* __restrict__ psum)
{
  const int wv   = threadIdx.x >> 6;
  const int lane = threadIdx.x & 63;
  const int g    = lane >> 4;      // quad 0..3
  const int c    = lane & 15;
  const int seg  = blockIdx.x;
  const int head = blockIdx.z;
  const int q0   = (blockIdx.y * 4 + wv) * 16;

  // B-layout Q^T fragment == row-major 16B load of Q (scale pre-folded)
  const short8 qf = *(const short8*)(Qb + (size_t)(q0 + c) * D + head * HD + g * 8);

  floatx4 accL = {0.f, 0.f, 0.f, 0.f};  // O^T feats 0..15
  floatx4 accH = {0.f, 0.f, 0.f, 0.f};  // O^T feats 16..31
  float ssum = 0.f;

  const int key0 = seg * SEG;
  const unsigned short* kb  = Kb  + (size_t)key0 * D + head * HD + g * 8;
  // V^T A-fragment bases: lane(g,c) reads keys (kc + 4g .. +3) of feat row
  const unsigned short* vlo = Vtb + (size_t)(head * HD + c) * N + key0 + g * 4;
  const unsigned short* vhi = vlo + (size_t)16 * N;

  short8 kf0 = *(const short8*)(kb + (size_t)c * D);
  short8 kf1 = *(const short8*)(kb + (size_t)(16 + c) * D);

  for (int kc = 0; kc < SEG; kc += 32) {
    const int nk = (kc + 32 < SEG) ? kc + 32 : 0;   // harmless reload on last
    short8 nkf0 = *(const short8*)(kb + (size_t)(nk + c) * D);
    short8 nkf1 = *(const short8*)(kb + (size_t)(nk + 16 + c) * D);
    // V^T fragments for this iteration's two 16-key chunks
    const bf16x4 vl0 = *(const bf16x4*)(vlo + kc);
    const bf16x4 vl1 = *(const bf16x4*)(vlo + kc + 16);
    const bf16x4 vh0 = *(const bf16x4*)(vhi + kc);
    const bf16x4 vh1 = *(const bf16x4*)(vhi + kc + 16);

    const floatx4 z = {0.f, 0.f, 0.f, 0.f};
    // S^T: rows = keys, cols = queries
    floatx4 sA = __builtin_amdgcn_mfma_f32_16x16x32_bf16(kf0, qf, z, 0, 0, 0);
    floatx4 sB = __builtin_amdgcn_mfma_f32_16x16x32_bf16(kf1, qf, z, 0, 0, 0);

    float pa[4], pb[4];
    #pragma unroll
    for (int r = 0; r < 4; ++r) {
      pa[r] = __expf(sA[r]);
      pb[r] = __expf(sB[r]);
      ssum += pa[r] + pb[r];
    }
    union { unsigned u[2]; bf16x4 s; } pA, pB;
    pA.u[0] = pack2bf(pa[0], pa[1]);
    pA.u[1] = pack2bf(pa[2], pa[3]);
    pB.u[0] = pack2bf(pb[0], pb[1]);
    pB.u[1] = pack2bf(pb[2], pb[3]);

    accL = __builtin_amdgcn_mfma_f32_16x16x16bf16_1k(vl0, pA.s, accL, 0, 0, 0);
    accL = __builtin_amdgcn_mfma_f32_16x16x16bf16_1k(vl1, pB.s, accL, 0, 0, 0);
    accH = __builtin_amdgcn_mfma_f32_16x16x16bf16_1k(vh0, pA.s, accH, 0, 0, 0);
    accH = __builtin_amdgcn_mfma_f32_16x16x16bf16_1k(vh1, pB.s, accH, 0, 0, 0);

    kf0 = nkf0; kf1 = nkf1;
  }

  // per-query partial sums are split across quads; reduce
  ssum += __shfl_xor(ssum, 16);
  ssum += __shfl_xor(ssum, 32);

  const size_t row = (size_t)(seg * NH + head) * N + q0 + c;
  float4 o0 = make_float4(accL[0], accL[1], accL[2], accL[3]);
  float4 o1 = make_float4(accH[0], accH[1], accH[2], accH[3]);
  *(float4*)(pacc + row * HD + g * 4)      = o0;   // feats 4g..4g+3
  *(float4*)(pacc + row * HD + 16 + g * 4) = o1;   // feats 16+4g..
  if (g == 0) psum[row] = ssum;
}

// ---------------- Combine key segments, write o (N, 256) ---------------------
__global__ __launch_bounds__(256) void combine_kernel(
    const float* __restrict__ pacc, const float* __restrict__ psum,
    float* __restrict__ o)
{
  const int n = blockIdx.x;
  const int t = threadIdx.x;
  const int h = t >> 5;
  const int d = t & 31;
  float num = 0.f, den = 0.f;
  #pragma unroll
  for (int sgi = 0; sgi < KS; ++sgi) {
    const size_t b = (size_t)(sgi * NH + h) * N + n;
    num += pacc[b * HD + d];
    den += psum[b];
  }
  o[(size_t)n * D + t] = num / den;
}

// ---------------- Out projection (fp32) --------------------------------------
__global__ __launch_bounds__(256) void gemm_kernel(
    const float* __restrict__ A, const float* __restrict__ W,
    const float* __restrict__ bias, float* __restrict__ C)
{
  __shared__ float As[64][68];
  __shared__ float Ws[64][68];
  const int t  = threadIdx.x;
  const int tx = t & 15;
  const int ty = t >> 4;
  const int j0 = blockIdx.x * 64;
  const int m0 = blockIdx.y * 64;

  float acc[4][4];
  #pragma unroll
  for (int r = 0; r < 4; ++r)
    #pragma unroll
    for (int c = 0; c < 4; ++c) acc[r][c] = 0.f;

  for (int kc = 0; kc < D; kc += 64) {
    const int col = tx * 4;
    #pragma unroll
    for (int i = 0; i < 4; ++i) {
      const int r = ty + 16 * i;
      *(float4*)&As[r][col] = *(const float4*)(A + (size_t)(m0 + r) * D + kc + col);
      *(float4*)&Ws[r][col] = *(const float4*)(W + (size_t)(j0 + r) * D + kc + col);
    }
    __syncthreads();
    #pragma unroll 4
    for (int kk = 0; kk < 64; kk += 4) {
      float4 a4[4], b4[4];
      #pragma unroll
      for (int r = 0; r < 4; ++r) a4[r] = *(const float4*)&As[ty * 4 + r][kk];
      #pragma unroll
      for (int c = 0; c < 4; ++c) b4[c] = *(const float4*)&Ws[tx + 16 * c][kk];
      #pragma unroll
      for (int r = 0; r < 4; ++r)
        #pragma unroll
        for (int c = 0; c < 4; ++c) {
          acc[r][c] += a4[r].x * b4[c].x;
          acc[r][c] += a4[r].y * b4[c].y;
          acc[r][c] += a4[r].z * b4[c].z;
          acc[r][c] += a4[r].w * b4[c].w;
        }
    }
    __syncthreads();
  }
  #pragma unroll
  for (int r = 0; r < 4; ++r) {
    const int m = m0 + ty * 4 + r;
    #pragma unroll
    for (int c = 0; c < 4; ++c) {
      const int j = j0 + tx + 16 * c;
      C[(size_t)m * D + j] = acc[r][c] + bias[j];
    }
  }
}

extern "C" void kernel_launch(void* const* d_in, const int* in_sizes, int n_in,
                              void* d_out, int out_size, void* d_ws, size_t ws_size,
                              hipStream_t stream)
{
  (void)in_sizes; (void)n_in; (void)out_size; (void)ws_size;
  const float* x1  = (const float*)d_in[0];
  const float* x2  = (const float*)d_in[1];
  const float* lng = (const float*)d_in[2];
  const float* lnb = (const float*)d_in[3];
  const float* ipw = (const float*)d_in[4];
  const float* ipb = (const float*)d_in[5];
  const float* ow  = (const float*)d_in[6];
  const float* ob  = (const float*)d_in[7];
  float* out = (float*)d_out;

  char* p = (char*)d_ws;
  float* x2f  = (float*)p; p += (size_t)N * D * 4;
  float* o    = (float*)p; p += (size_t)N * D * 4;
  float* pacc = (float*)p; p += (size_t)KS * NH * N * HD * 4;
  float* psum = (float*)p; p += (size_t)KS * NH * N * 4;
  unsigned short* Qb  = (unsigned short*)p; p += (size_t)N * D * 2;
  unsigned short* Kb  = (unsigned short*)p; p += (size_t)N * D * 2;
  unsigned short* Vtb = (unsigned short*)p; p += (size_t)D * N * 2;
  unsigned short* x2b_full = (unsigned short*)p; p += (size_t)NGR * D * 2;
  unsigned short* x2t_full = (unsigned short*)p; p += (size_t)D * NGR * 2;
  const unsigned short* x2b = x2b_full + (size_t)8 * D;
  const unsigned short* x2t = x2t_full + 8;

  prep_kernel<<<dim3(NGR / 16, 16), 256, 0, stream>>>(x2, x2b_full, x2t_full);
  stage1_mfma_kernel<<<144, 256, 0, stream>>>(x2b, x2t, lng, lnb, x2f);
  gemm_qkv_kernel<<<dim3(12, 36), 256, 0, stream>>>(x2f, x1, ipw, ipb, Qb, Kb, Vtb);
  attn_mfma_kernel<<<dim3(KS, 36, NH), 256, 0, stream>>>(Qb, Kb, Vtb, pacc, psum);
  combine_kernel<<<N, 256, 0, stream>>>(pacc, psum, o);
  gemm_kernel<<<dim3(4, 36), 256, 0, stream>>>(o, ow, ob, out);
}

// Round 7
// 165.556 us; speedup vs baseline: 1.2380x; 1.2380x over previous
//
#include <hip/hip_runtime.h>
#include <math.h>

#define N 2304
#define D 256
#define K_NB 289
#define NH 8
#define HD 32
#define KS 8            // key segments in attention
#define SEG (N / KS)    // 288
#define NGR 2320        // guarded key count (2304 + 8 each side)

typedef __attribute__((ext_vector_type(8))) short short8;   // 8 bf16
typedef __attribute__((ext_vector_type(4))) short bf16x4;   // 4 bf16
typedef __attribute__((ext_vector_type(4))) float floatx4;  // 4 fp32 (MFMA C/D)

static __device__ __forceinline__ unsigned short f2bf(float x) {
  union { float f; unsigned u; } v; v.f = x;
  unsigned r = (v.u + 0x7fffu + ((v.u >> 16) & 1u)) >> 16;   // RNE
  return (unsigned short)r;
}
static __device__ __forceinline__ unsigned pack2bf(float lo, float hi) {
  return (unsigned)f2bf(lo) | ((unsigned)f2bf(hi) << 16);
}

// ---------------- Prep: x2 fp32 -> bf16 row-major + transposed, zero guards --
__global__ __launch_bounds__(256) void prep_kernel(
    const float* __restrict__ x2, unsigned short* __restrict__ x2b_full,
    unsigned short* __restrict__ x2t_full)
{
  __shared__ unsigned short T[16][17];
  const int tx = threadIdx.x & 15;
  const int ty = threadIdx.x >> 4;
  const int k0 = blockIdx.x * 16;
  const int f0 = blockIdx.y * 16;
  const int key = k0 + ty - 8;
  unsigned short v = 0;
  if (key >= 0 && key < N) v = f2bf(x2[(size_t)key * D + f0 + tx]);
  x2b_full[(size_t)(k0 + ty) * D + f0 + tx] = v;
  T[ty][tx] = v;
  __syncthreads();
  x2t_full[(size_t)(f0 + ty) * NGR + k0 + tx] = T[tx][ty];
}

// ---------------- Stage 1: MFMA window attention + layernorm -----------------
__global__ __launch_bounds__(256) void stage1_mfma_kernel(
    const unsigned short* __restrict__ x2b,
    const unsigned short* __restrict__ x2t,
    const float* __restrict__ gamma, const float* __restrict__ beta,
    float* __restrict__ x2f)
{
  __shared__ float S[16][548];
  __shared__ __align__(16) unsigned short Pb[16][552];
  __shared__ float dinv[16];
  __shared__ float lr1[4][16], lr2[4][16];

  const int t    = threadIdx.x;
  const int w    = t >> 6;
  const int lane = t & 63;
  const int g    = lane >> 4;
  const int cL   = lane & 15;
  const int b  = blockIdx.x;
  const int r  = b / 3;
  const int c0 = (b % 3) * 16;
  const int qbase = r * 48 + c0;
  const int row_lo = max(0, 8 - r);
  const int row_hi = min(16, 55 - r);

  short8 qf[8];
  {
    const unsigned short* qptr = x2b + (size_t)(qbase + cL) * D + g * 8;
    #pragma unroll
    for (int s = 0; s < 8; ++s) qf[s] = *(const short8*)(qptr + s * 32);
  }

  for (int wr = row_lo + w; wr <= row_hi; wr += 4) {
    const int kr = r - 8 + wr;
    const int keybase = kr * 48 + c0 - 8;
    #pragma unroll
    for (int ch = 0; ch < 2; ++ch) {
      const unsigned short* kptr = x2b + (size_t)(keybase + ch * 16 + cL) * D + g * 8;
      floatx4 sa = {0.f, 0.f, 0.f, 0.f};
      #pragma unroll
      for (int s = 0; s < 8; ++s) {
        const short8 kf = *(const short8*)(kptr + s * 32);
        sa = __builtin_amdgcn_mfma_f32_16x16x32_bf16(qf[s], kf, sa, 0, 0, 0);
      }
      #pragma unroll
      for (int reg = 0; reg < 4; ++reg)
        S[g * 4 + reg][wr * 32 + ch * 16 + cL] = sa[reg] * 0.0625f;
    }
  }
  __syncthreads();

  if (t < 16) {
    const int c = c0 + t;
    const int nrows = min(r + 8, 47) - max(r - 8, 0) + 1;
    const int ncols = min(c + 8, 47) - max(c - 8, 0) + 1;
    const int mult  = K_NB - nrows * ncols + 1;
    if (mult > 1) {
      const int wr0 = max(0, 8 - r);
      const int wc0 = (c >= 8) ? t : (8 - c0);
      S[t][wr0 * 32 + wc0] += __logf((float)mult);
    }
  }
  __syncthreads();

  {
    const int qi = t >> 4, ti = t & 15;
    float ssum = 0.f;
    for (int wk = ti; wk < 544; wk += 16) {
      const int wr = wk >> 5, wc = wk & 31;
      const int kr = r - 8 + wr;
      const int kc = c0 - 8 + wc;
      const bool valid = (kr >= 0) & (kr < 48) & (kc >= 0) & (kc < 48) &
                         (wc >= qi) & (wc <= qi + 16);
      const float p = valid ? __expf(S[qi][wk]) : 0.f;
      ssum += p;
      Pb[qi][wk] = valid ? f2bf(p) : (unsigned short)0;
    }
    #pragma unroll
    for (int off = 1; off <= 8; off <<= 1) ssum += __shfl_xor(ssum, off);
    if (ti == 0) dinv[qi] = 1.f / ssum;
  }
  __syncthreads();

  floatx4 acc[4];
  #pragma unroll
  for (int ng = 0; ng < 4; ++ng) acc[ng] = (floatx4){0.f, 0.f, 0.f, 0.f};
  const int fb = w * 64;
  for (int wr = row_lo; wr <= row_hi; ++wr) {
    const int keybase = (r - 8 + wr) * 48 + c0 - 8;
    const short8 pA = *(const short8*)&Pb[cL][wr * 32 + g * 8];
    #pragma unroll
    for (int ng = 0; ng < 4; ++ng) {
      const short8 vf = *(const short8*)(x2t + (size_t)(fb + ng * 16 + cL) * NGR + keybase + g * 8);
      acc[ng] = __builtin_amdgcn_mfma_f32_16x16x32_bf16(pA, vf, acc[ng], 0, 0, 0);
    }
  }

  float vout[4][4], ps1[4] = {0,0,0,0}, ps2[4] = {0,0,0,0};
  #pragma unroll
  for (int reg = 0; reg < 4; ++reg) {
    const float di = dinv[g * 4 + reg];
    #pragma unroll
    for (int ng = 0; ng < 4; ++ng) {
      const float v = acc[ng][reg] * di;
      vout[ng][reg] = v;
      ps1[reg] += v;
      ps2[reg] += v * v;
    }
  }
  #pragma unroll
  for (int off = 1; off <= 8; off <<= 1) {
    #pragma unroll
    for (int reg = 0; reg < 4; ++reg) {
      ps1[reg] += __shfl_xor(ps1[reg], off);
      ps2[reg] += __shfl_xor(ps2[reg], off);
    }
  }
  if (cL == 0) {
    #pragma unroll
    for (int reg = 0; reg < 4; ++reg) {
      lr1[w][g * 4 + reg] = ps1[reg];
      lr2[w][g * 4 + reg] = ps2[reg];
    }
  }
  __syncthreads();
  #pragma unroll
  for (int reg = 0; reg < 4; ++reg) {
    const int m = g * 4 + reg;
    const float s1 = lr1[0][m] + lr1[1][m] + lr1[2][m] + lr1[3][m];
    const float s2 = lr2[0][m] + lr2[1][m] + lr2[2][m] + lr2[3][m];
    const float mu  = s1 * (1.f / 256.f);
    const float var = s2 * (1.f / 256.f) - mu * mu;
    const float rs  = rsqrtf(var + 1e-5f);
    #pragma unroll
    for (int ng = 0; ng < 4; ++ng) {
      const int f = fb + ng * 16 + cL;
      x2f[(size_t)(qbase + m) * D + f] = (vout[ng][reg] - mu) * rs * gamma[f] + beta[f];
    }
  }
}

// ---------------- QKV projection (fp32 core, bf16 epilogue) ------------------
__global__ __launch_bounds__(256) void gemm_qkv_kernel(
    const float* __restrict__ A0, const float* __restrict__ A1,
    const float* __restrict__ W, const float* __restrict__ bias,
    unsigned short* __restrict__ Qb, unsigned short* __restrict__ Kb,
    unsigned short* __restrict__ Vtb)
{
  __shared__ float As[64][68];
  __shared__ float Ws[64][68];
  const int t  = threadIdx.x;
  const int tx = t & 15;
  const int ty = t >> 4;
  const int j0 = blockIdx.x * 64;
  const int m0 = blockIdx.y * 64;
  const float* __restrict__ Asrc = (j0 < 256) ? A0 : A1;

  float acc[4][4];
  #pragma unroll
  for (int r = 0; r < 4; ++r)
    #pragma unroll
    for (int c = 0; c < 4; ++c) acc[r][c] = 0.f;

  for (int kc = 0; kc < D; kc += 64) {
    const int col = tx * 4;
    #pragma unroll
    for (int i = 0; i < 4; ++i) {
      const int r = ty + 16 * i;
      *(float4*)&As[r][col] = *(const float4*)(Asrc + (size_t)(m0 + r) * D + kc + col);
      *(float4*)&Ws[r][col] = *(const float4*)(W    + (size_t)(j0 + r) * D + kc + col);
    }
    __syncthreads();
    #pragma unroll 4
    for (int kk = 0; kk < 64; kk += 4) {
      float4 a4[4], b4[4];
      #pragma unroll
      for (int r = 0; r < 4; ++r) a4[r] = *(const float4*)&As[ty * 4 + r][kk];
      #pragma unroll
      for (int c = 0; c < 4; ++c) b4[c] = *(const float4*)&Ws[tx + 16 * c][kk];
      #pragma unroll
      for (int r = 0; r < 4; ++r)
        #pragma unroll
        for (int c = 0; c < 4; ++c) {
          acc[r][c] += a4[r].x * b4[c].x;
          acc[r][c] += a4[r].y * b4[c].y;
          acc[r][c] += a4[r].z * b4[c].z;
          acc[r][c] += a4[r].w * b4[c].w;
        }
    }
    __syncthreads();
  }
  const float qscale = 0.17677669529663687f;
  #pragma unroll
  for (int r = 0; r < 4; ++r) {
    const int m = m0 + ty * 4 + r;
    #pragma unroll
    for (int c = 0; c < 4; ++c) {
      const int j = j0 + tx + 16 * c;
      const float v = acc[r][c] + bias[j];
      if (j0 < 256)       Qb[(size_t)m * D + j] = f2bf(v * qscale);
      else if (j0 < 512)  Kb[(size_t)m * D + (j - 256)] = f2bf(v);
      else                Vtb[(size_t)(j - 512) * N + m] = f2bf(v);
    }
  }
}

// ---------------- MFMA flash attention: LDS-staged, fat waves ----------------
// Block = 128 threads (2 waves); wave owns 64 queries (4 q-tiles) of one head;
// block iterates its key segment in 32-key chunks staged to double-buffered
// LDS (K key-major, V^T feat-major, rows padded to 80 B). Math per chunk:
// S^T = K·Q^T (x32 MFMA) -> exp -> packed probs feed x16 PV directly as the
// B operand (B[k=quad*4+j][n=lane&15] == S^T C-layout). No transposes.
__global__ __launch_bounds__(128) void attn_mfma_kernel(
    const unsigned short* __restrict__ Qb, const unsigned short* __restrict__ Kb,
    const unsigned short* __restrict__ Vtb,
    float* __restrict__ pacc, float* __restrict__ psum)
{
  __shared__ __align__(16) unsigned short Ksh[2][32 * 40];  // [key][feat], 80B rows
  __shared__ __align__(16) unsigned short Vsh[2][32 * 40];  // [feat][key], 80B rows

  const int t    = threadIdx.x;
  const int wv   = t >> 6;
  const int lane = t & 63;
  const int g    = lane >> 4;      // quad
  const int c    = lane & 15;
  const int seg  = blockIdx.x;
  const int qb   = blockIdx.y;
  const int head = blockIdx.z;
  const int q0w  = qb * 128 + wv * 64;
  const int key0 = seg * SEG;

  // Q^T B-fragments for 4 q-tiles (scale pre-folded into Qb)
  short8 qf[4];
  #pragma unroll
  for (int qt = 0; qt < 4; ++qt)
    qf[qt] = *(const short8*)(Qb + (size_t)(q0w + qt * 16 + c) * D + head * HD + g * 8);

  // staging: thread t moves 16B of K (key t/4, feats (t%4)*8..) and 16B of
  // V^T (feat t/4, keys (t%4)*8..) per chunk
  const unsigned short* ksrc = Kb  + (size_t)(key0 + t / 4) * D + head * HD + (t % 4) * 8;
  const unsigned short* vsrc = Vtb + (size_t)(head * HD + t / 4) * N + key0 + (t % 4) * 8;
  const int sdst = (t / 4) * 40 + (t % 4) * 8;   // shorts

  {
    const float4 gk = *(const float4*)ksrc;
    const float4 gv = *(const float4*)vsrc;
    *(float4*)&Ksh[0][sdst] = gk;
    *(float4*)&Vsh[0][sdst] = gv;
  }
  __syncthreads();

  floatx4 accL[4], accH[4];
  float ssum[4];
  #pragma unroll
  for (int qt = 0; qt < 4; ++qt) {
    accL[qt] = (floatx4){0.f, 0.f, 0.f, 0.f};
    accH[qt] = (floatx4){0.f, 0.f, 0.f, 0.f};
    ssum[qt] = 0.f;
  }

  const int NCH = SEG / 32;   // 9
  for (int ch = 0; ch < NCH; ++ch) {
    float4 gk, gv;
    const bool more = (ch + 1 < NCH);
    if (more) {
      gk = *(const float4*)(ksrc + (size_t)(ch + 1) * 32 * D);
      gv = *(const float4*)(vsrc + (ch + 1) * 32);
    }
    const unsigned short* kb = Ksh[ch & 1];
    const unsigned short* vb = Vsh[ch & 1];

    #pragma unroll
    for (int kk = 0; kk < 2; ++kk) {
      const short8 kf  = *(const short8*)&kb[(kk * 16 + c) * 40 + g * 8];
      const bf16x4 vf0 = *(const bf16x4*)&vb[c * 40 + kk * 16 + g * 4];
      const bf16x4 vf1 = *(const bf16x4*)&vb[(16 + c) * 40 + kk * 16 + g * 4];
      #pragma unroll
      for (int qt = 0; qt < 4; ++qt) {
        const floatx4 z = {0.f, 0.f, 0.f, 0.f};
        floatx4 sA = __builtin_amdgcn_mfma_f32_16x16x32_bf16(kf, qf[qt], z, 0, 0, 0);
        const float p0 = __expf(sA[0]);
        const float p1 = __expf(sA[1]);
        const float p2 = __expf(sA[2]);
        const float p3 = __expf(sA[3]);
        ssum[qt] += (p0 + p1) + (p2 + p3);
        union { unsigned u[2]; bf16x4 s; } pB;
        pB.u[0] = pack2bf(p0, p1);
        pB.u[1] = pack2bf(p2, p3);
        accL[qt] = __builtin_amdgcn_mfma_f32_16x16x16bf16_1k(vf0, pB.s, accL[qt], 0, 0, 0);
        accH[qt] = __builtin_amdgcn_mfma_f32_16x16x16bf16_1k(vf1, pB.s, accH[qt], 0, 0, 0);
      }
    }
    if (more) {
      *(float4*)&Ksh[(ch + 1) & 1][sdst] = gk;
      *(float4*)&Vsh[(ch + 1) & 1][sdst] = gv;
    }
    __syncthreads();
  }

  #pragma unroll
  for (int qt = 0; qt < 4; ++qt) {
    float s = ssum[qt];
    s += __shfl_xor(s, 16);
    s += __shfl_xor(s, 32);
    const size_t row = (size_t)(seg * NH + head) * N + q0w + qt * 16 + c;
    *(float4*)(pacc + row * HD + g * 4) =
        make_float4(accL[qt][0], accL[qt][1], accL[qt][2], accL[qt][3]);
    *(float4*)(pacc + row * HD + 16 + g * 4) =
        make_float4(accH[qt][0], accH[qt][1], accH[qt][2], accH[qt][3]);
    if (g == 0) psum[row] = s;
  }
}

// ---------------- Combine key segments, write o (N, 256) ---------------------
__global__ __launch_bounds__(256) void combine_kernel(
    const float* __restrict__ pacc, const float* __restrict__ psum,
    float* __restrict__ o)
{
  const int n = blockIdx.x;
  const int t = threadIdx.x;
  const int h = t >> 5;
  const int d = t & 31;
  float num = 0.f, den = 0.f;
  #pragma unroll
  for (int sgi = 0; sgi < KS; ++sgi) {
    const size_t b = (size_t)(sgi * NH + h) * N + n;
    num += pacc[b * HD + d];
    den += psum[b];
  }
  o[(size_t)n * D + t] = num / den;
}

// ---------------- Out projection (fp32) --------------------------------------
__global__ __launch_bounds__(256) void gemm_kernel(
    const float* __restrict__ A, const float* __restrict__ W,
    const float* __restrict__ bias, float* __restrict__ C)
{
  __shared__ float As[64][68];
  __shared__ float Ws[64][68];
  const int t  = threadIdx.x;
  const int tx = t & 15;
  const int ty = t >> 4;
  const int j0 = blockIdx.x * 64;
  const int m0 = blockIdx.y * 64;

  float acc[4][4];
  #pragma unroll
  for (int r = 0; r < 4; ++r)
    #pragma unroll
    for (int c = 0; c < 4; ++c) acc[r][c] = 0.f;

  for (int kc = 0; kc < D; kc += 64) {
    const int col = tx * 4;
    #pragma unroll
    for (int i = 0; i < 4; ++i) {
      const int r = ty + 16 * i;
      *(float4*)&As[r][col] = *(const float4*)(A + (size_t)(m0 + r) * D + kc + col);
      *(float4*)&Ws[r][col] = *(const float4*)(W + (size_t)(j0 + r) * D + kc + col);
    }
    __syncthreads();
    #pragma unroll 4
    for (int kk = 0; kk < 64; kk += 4) {
      float4 a4[4], b4[4];
      #pragma unroll
      for (int r = 0; r < 4; ++r) a4[r] = *(const float4*)&As[ty * 4 + r][kk];
      #pragma unroll
      for (int c = 0; c < 4; ++c) b4[c] = *(const float4*)&Ws[tx + 16 * c][kk];
      #pragma unroll
      for (int r = 0; r < 4; ++r)
        #pragma unroll
        for (int c = 0; c < 4; ++c) {
          acc[r][c] += a4[r].x * b4[c].x;
          acc[r][c] += a4[r].y * b4[c].y;
          acc[r][c] += a4[r].z * b4[c].z;
          acc[r][c] += a4[r].w * b4[c].w;
        }
    }
    __syncthreads();
  }
  #pragma unroll
  for (int r = 0; r < 4; ++r) {
    const int m = m0 + ty * 4 + r;
    #pragma unroll
    for (int c = 0; c < 4; ++c) {
      const int j = j0 + tx + 16 * c;
      C[(size_t)m * D + j] = acc[r][c] + bias[j];
    }
  }
}

extern "C" void kernel_launch(void* const* d_in, const int* in_sizes, int n_in,
                              void* d_out, int out_size, void* d_ws, size_t ws_size,
                              hipStream_t stream)
{
  (void)in_sizes; (void)n_in; (void)out_size; (void)ws_size;
  const float* x1  = (const float*)d_in[0];
  const float* x2  = (const float*)d_in[1];
  const float* lng = (const float*)d_in[2];
  const float* lnb = (const float*)d_in[3];
  const float* ipw = (const float*)d_in[4];
  const float* ipb = (const float*)d_in[5];
  const float* ow  = (const float*)d_in[6];
  const float* ob  = (const float*)d_in[7];
  float* out = (float*)d_out;

  char* p = (char*)d_ws;
  float* x2f  = (float*)p; p += (size_t)N * D * 4;
  float* o    = (float*)p; p += (size_t)N * D * 4;
  float* pacc = (float*)p; p += (size_t)KS * NH * N * HD * 4;
  float* psum = (float*)p; p += (size_t)KS * NH * N * 4;
  unsigned short* Qb  = (unsigned short*)p; p += (size_t)N * D * 2;
  unsigned short* Kb  = (unsigned short*)p; p += (size_t)N * D * 2;
  unsigned short* Vtb = (unsigned short*)p; p += (size_t)D * N * 2;
  unsigned short* x2b_full = (unsigned short*)p; p += (size_t)NGR * D * 2;
  unsigned short* x2t_full = (unsigned short*)p; p += (size_t)D * NGR * 2;
  const unsigned short* x2b = x2b_full + (size_t)8 * D;
  const unsigned short* x2t = x2t_full + 8;

  prep_kernel<<<dim3(NGR / 16, 16), 256, 0, stream>>>(x2, x2b_full, x2t_full);
  stage1_mfma_kernel<<<144, 256, 0, stream>>>(x2b, x2t, lng, lnb, x2f);
  gemm_qkv_kernel<<<dim3(12, 36), 256, 0, stream>>>(x2f, x1, ipw, ipb, Qb, Kb, Vtb);
  attn_mfma_kernel<<<dim3(KS, N / 128, NH), 128, 0, stream>>>(Qb, Kb, Vtb, pacc, psum);
  combine_kernel<<<N, 256, 0, stream>>>(pacc, psum, o);
  gemm_kernel<<<dim3(4, 36), 256, 0, stream>>>(o, ow, ob, out);
}

// Round 8
// 161.078 us; speedup vs baseline: 1.2724x; 1.0278x over previous
//
#include <hip/hip_runtime.h>
#include <math.h>

#define N 2304
#define D 256
#define K_NB 289
#define NH 8
#define HD 32
#define KS 8            // key segments in attention
#define SEG (N / KS)    // 288
#define NGR 2320        // guarded key count (2304 + 8 each side)

typedef __attribute__((ext_vector_type(8))) short short8;   // 8 bf16
typedef __attribute__((ext_vector_type(4))) short bf16x4;   // 4 bf16
typedef __attribute__((ext_vector_type(4))) float floatx4;  // 4 fp32 (MFMA C/D)

static __device__ __forceinline__ unsigned short f2bf(float x) {
  union { float f; unsigned u; } v; v.f = x;
  unsigned r = (v.u + 0x7fffu + ((v.u >> 16) & 1u)) >> 16;   // RNE
  return (unsigned short)r;
}
static __device__ __forceinline__ float bf2f(unsigned short h) {
  union { unsigned u; float f; } v; v.u = (unsigned)h << 16;
  return v.f;
}
static __device__ __forceinline__ unsigned pack2bf(float lo, float hi) {
  return (unsigned)f2bf(lo) | ((unsigned)f2bf(hi) << 16);
}

// ---------------- hi/lo bf16 split of x1, in_proj_w, out_w -------------------
#define CV_X1 (N * D)              // 589824
#define CV_W  (768 * 256)          // 196608
#define CV_OW (256 * 256)          // 65536
__global__ __launch_bounds__(256) void conv_hilo_kernel(
    const float* __restrict__ x1, const float* __restrict__ ipw,
    const float* __restrict__ ow,
    unsigned short* __restrict__ x1h, unsigned short* __restrict__ x1l,
    unsigned short* __restrict__ wh,  unsigned short* __restrict__ wl,
    unsigned short* __restrict__ owh, unsigned short* __restrict__ owl)
{
  int i = blockIdx.x * 256 + threadIdx.x;
  const float* src; unsigned short *dh, *dl; int off;
  if (i < CV_X1)            { src = x1;  dh = x1h; dl = x1l; off = i; }
  else if (i < CV_X1 + CV_W){ src = ipw; dh = wh;  dl = wl;  off = i - CV_X1; }
  else                      { src = ow;  dh = owh; dl = owl; off = i - CV_X1 - CV_W; }
  const float v = src[off];
  const unsigned short h = f2bf(v);
  dh[off] = h;
  dl[off] = f2bf(v - bf2f(h));
}

// ---------------- Prep: x2 fp32 -> bf16 row-major + transposed, zero guards --
__global__ __launch_bounds__(256) void prep_kernel(
    const float* __restrict__ x2, unsigned short* __restrict__ x2b_full,
    unsigned short* __restrict__ x2t_full)
{
  __shared__ unsigned short T[16][17];
  const int tx = threadIdx.x & 15;
  const int ty = threadIdx.x >> 4;
  const int k0 = blockIdx.x * 16;
  const int f0 = blockIdx.y * 16;
  const int key = k0 + ty - 8;
  unsigned short v = 0;
  if (key >= 0 && key < N) v = f2bf(x2[(size_t)key * D + f0 + tx]);
  x2b_full[(size_t)(k0 + ty) * D + f0 + tx] = v;
  T[ty][tx] = v;
  __syncthreads();
  x2t_full[(size_t)(f0 + ty) * NGR + k0 + tx] = T[tx][ty];
}

// ---------------- Stage 1: MFMA window attention + layernorm (8 waves) -------
// One block = 16 consecutive queries in an image row; 512 threads.
// Output: x2f as hi/lo bf16 (fp32-equivalent for the split-GEMM consumer).
__global__ __launch_bounds__(512) void stage1_mfma_kernel(
    const unsigned short* __restrict__ x2b,
    const unsigned short* __restrict__ x2t,
    const float* __restrict__ gamma, const float* __restrict__ beta,
    unsigned short* __restrict__ x2fh, unsigned short* __restrict__ x2fl)
{
  __shared__ float S[16][548];
  __shared__ __align__(16) unsigned short Pb[16][552];
  __shared__ float dinv[16];
  __shared__ float lr1[8][16], lr2[8][16];

  const int t    = threadIdx.x;
  const int w    = t >> 6;         // 0..7
  const int lane = t & 63;
  const int g    = lane >> 4;
  const int cL   = lane & 15;
  const int b  = blockIdx.x;
  const int r  = b / 3;
  const int c0 = (b % 3) * 16;
  const int qbase = r * 48 + c0;
  const int row_lo = max(0, 8 - r);
  const int row_hi = min(16, 55 - r);

  short8 qf[8];
  {
    const unsigned short* qptr = x2b + (size_t)(qbase + cL) * D + g * 8;
    #pragma unroll
    for (int s = 0; s < 8; ++s) qf[s] = *(const short8*)(qptr + s * 32);
  }

  // ---- scores: 8 waves split window rows ----
  for (int wr = row_lo + w; wr <= row_hi; wr += 8) {
    const int kr = r - 8 + wr;
    const int keybase = kr * 48 + c0 - 8;
    #pragma unroll
    for (int ch = 0; ch < 2; ++ch) {
      const unsigned short* kptr = x2b + (size_t)(keybase + ch * 16 + cL) * D + g * 8;
      floatx4 sa = {0.f, 0.f, 0.f, 0.f};
      #pragma unroll
      for (int s = 0; s < 8; ++s) {
        const short8 kf = *(const short8*)(kptr + s * 32);
        sa = __builtin_amdgcn_mfma_f32_16x16x32_bf16(qf[s], kf, sa, 0, 0, 0);
      }
      #pragma unroll
      for (int reg = 0; reg < 4; ++reg)
        S[g * 4 + reg][wr * 32 + ch * 16 + cL] = sa[reg] * 0.0625f;
    }
  }
  __syncthreads();

  if (t < 16) {
    const int c = c0 + t;
    const int nrows = min(r + 8, 47) - max(r - 8, 0) + 1;
    const int ncols = min(c + 8, 47) - max(c - 8, 0) + 1;
    const int mult  = K_NB - nrows * ncols + 1;
    if (mult > 1) {
      const int wr0 = max(0, 8 - r);
      const int wc0 = (c >= 8) ? t : (8 - c0);
      S[t][wr0 * 32 + wc0] += __logf((float)mult);
    }
  }
  __syncthreads();

  // ---- masked exp + row sums; 32 threads per query ----
  {
    const int qi = t >> 5, ti = t & 31;
    float ssum = 0.f;
    for (int wk = ti; wk < 544; wk += 32) {
      const int wr = wk >> 5, wc = wk & 31;
      const int kr = r - 8 + wr;
      const int kc = c0 - 8 + wc;
      const bool valid = (kr >= 0) & (kr < 48) & (kc >= 0) & (kc < 48) &
                         (wc >= qi) & (wc <= qi + 16);
      const float p = valid ? __expf(S[qi][wk]) : 0.f;
      ssum += p;
      Pb[qi][wk] = valid ? f2bf(p) : (unsigned short)0;
    }
    #pragma unroll
    for (int off = 1; off <= 16; off <<= 1) ssum += __shfl_xor(ssum, off);
    if (ti == 0) dinv[qi] = 1.f / ssum;
  }
  __syncthreads();

  // ---- PV: wave w owns feats [w*32, w*32+32) ----
  floatx4 acc[2];
  acc[0] = (floatx4){0.f, 0.f, 0.f, 0.f};
  acc[1] = (floatx4){0.f, 0.f, 0.f, 0.f};
  const int fb = w * 32;
  for (int wr = row_lo; wr <= row_hi; ++wr) {
    const int keybase = (r - 8 + wr) * 48 + c0 - 8;
    const short8 pA = *(const short8*)&Pb[cL][wr * 32 + g * 8];
    #pragma unroll
    for (int ng = 0; ng < 2; ++ng) {
      const short8 vf = *(const short8*)(x2t + (size_t)(fb + ng * 16 + cL) * NGR + keybase + g * 8);
      acc[ng] = __builtin_amdgcn_mfma_f32_16x16x32_bf16(pA, vf, acc[ng], 0, 0, 0);
    }
  }

  // ---- epilogue: /denom, layernorm across 256 feats ----
  float vout[2][4], ps1[4] = {0,0,0,0}, ps2[4] = {0,0,0,0};
  #pragma unroll
  for (int reg = 0; reg < 4; ++reg) {
    const float di = dinv[g * 4 + reg];
    #pragma unroll
    for (int ng = 0; ng < 2; ++ng) {
      const float v = acc[ng][reg] * di;
      vout[ng][reg] = v;
      ps1[reg] += v;
      ps2[reg] += v * v;
    }
  }
  #pragma unroll
  for (int off = 1; off <= 8; off <<= 1) {
    #pragma unroll
    for (int reg = 0; reg < 4; ++reg) {
      ps1[reg] += __shfl_xor(ps1[reg], off);
      ps2[reg] += __shfl_xor(ps2[reg], off);
    }
  }
  if (cL == 0) {
    #pragma unroll
    for (int reg = 0; reg < 4; ++reg) {
      lr1[w][g * 4 + reg] = ps1[reg];
      lr2[w][g * 4 + reg] = ps2[reg];
    }
  }
  __syncthreads();
  #pragma unroll
  for (int reg = 0; reg < 4; ++reg) {
    const int m = g * 4 + reg;
    float s1 = 0.f, s2 = 0.f;
    #pragma unroll
    for (int ww = 0; ww < 8; ++ww) { s1 += lr1[ww][m]; s2 += lr2[ww][m]; }
    const float mu  = s1 * (1.f / 256.f);
    const float var = s2 * (1.f / 256.f) - mu * mu;
    const float rs  = rsqrtf(var + 1e-5f);
    #pragma unroll
    for (int ng = 0; ng < 2; ++ng) {
      const int f = fb + ng * 16 + cL;
      const float val = (vout[ng][reg] - mu) * rs * gamma[f] + beta[f];
      const unsigned short h = f2bf(val);
      const size_t idx = (size_t)(qbase + m) * D + f;
      x2fh[idx] = h;
      x2fl[idx] = f2bf(val - bf2f(h));
    }
  }
}

// ---------------- QKV projection: split-bf16 MFMA GEMM -----------------------
// C[m][j] = sum_d A[m][d] W[j][d] + bias[j], A = x2f (j<256) else x1, both as
// hi+lo bf16; 3 passes (Ah·Wh + Al·Wh + Ah·Wl) ~ fp32 accuracy.
// Block 256 thr = 4 waves; wave tile 64m x 32n; block tile 64m x 128n.
__global__ __launch_bounds__(256) void gemm_qkv_mfma(
    const unsigned short* __restrict__ x2fh, const unsigned short* __restrict__ x2fl,
    const unsigned short* __restrict__ x1h,  const unsigned short* __restrict__ x1l,
    const unsigned short* __restrict__ Wh,   const unsigned short* __restrict__ Wl,
    const float* __restrict__ bias,
    unsigned short* __restrict__ Qb, unsigned short* __restrict__ Kb,
    unsigned short* __restrict__ Vtb)
{
  const int t = threadIdx.x;
  const int wv = t >> 6, lane = t & 63, g = lane >> 4, c = lane & 15;
  const int n0 = blockIdx.x * 128;
  const int m0 = blockIdx.y * 64;
  const int nw = n0 + wv * 32;
  const unsigned short* Ah = (n0 < 256) ? x2fh : x1h;
  const unsigned short* Al = (n0 < 256) ? x2fl : x1l;

  floatx4 acc[4][2];
  #pragma unroll
  for (int mt = 0; mt < 4; ++mt)
    #pragma unroll
    for (int nt = 0; nt < 2; ++nt) acc[mt][nt] = (floatx4){0.f, 0.f, 0.f, 0.f};

  #pragma unroll
  for (int pass = 0; pass < 3; ++pass) {
    const unsigned short* Ap = (pass == 1) ? Al : Ah;
    const unsigned short* Wp = (pass == 2) ? Wl : Wh;
    for (int kc = 0; kc < 256; kc += 32) {
      short8 af[4], bf[2];
      #pragma unroll
      for (int mt = 0; mt < 4; ++mt)
        af[mt] = *(const short8*)(Ap + (size_t)(m0 + mt * 16 + c) * 256 + kc + g * 8);
      #pragma unroll
      for (int nt = 0; nt < 2; ++nt)
        bf[nt] = *(const short8*)(Wp + (size_t)(nw + nt * 16 + c) * 256 + kc + g * 8);
      #pragma unroll
      for (int mt = 0; mt < 4; ++mt)
        #pragma unroll
        for (int nt = 0; nt < 2; ++nt)
          acc[mt][nt] = __builtin_amdgcn_mfma_f32_16x16x32_bf16(af[mt], bf[nt], acc[mt][nt], 0, 0, 0);
    }
  }

  const float qscale = 0.17677669529663687f;  // 1/sqrt(32) folded into Q
  #pragma unroll
  for (int mt = 0; mt < 4; ++mt) {
    #pragma unroll
    for (int nt = 0; nt < 2; ++nt) {
      const int j = nw + nt * 16 + c;
      const float bj = bias[j];
      #pragma unroll
      for (int r = 0; r < 4; ++r) {
        const int m = m0 + mt * 16 + 4 * g + r;
        const float v = acc[mt][nt][r] + bj;
        if (j < 256)       Qb[(size_t)m * 256 + j] = f2bf(v * qscale);
        else if (j < 512)  Kb[(size_t)m * 256 + (j - 256)] = f2bf(v);
        else               Vtb[(size_t)(j - 512) * N + m] = f2bf(v);
      }
    }
  }
}

// ---------------- MFMA flash attention: LDS-staged, fat waves ----------------
__global__ __launch_bounds__(128) void attn_mfma_kernel(
    const unsigned short* __restrict__ Qb, const unsigned short* __restrict__ Kb,
    const unsigned short* __restrict__ Vtb,
    float* __restrict__ pacc, float* __restrict__ psum)
{
  __shared__ __align__(16) unsigned short Ksh[2][32 * 40];
  __shared__ __align__(16) unsigned short Vsh[2][32 * 40];

  const int t    = threadIdx.x;
  const int wv   = t >> 6;
  const int lane = t & 63;
  const int g    = lane >> 4;
  const int c    = lane & 15;
  const int seg  = blockIdx.x;
  const int qb   = blockIdx.y;
  const int head = blockIdx.z;
  const int q0w  = qb * 128 + wv * 64;
  const int key0 = seg * SEG;

  short8 qf[4];
  #pragma unroll
  for (int qt = 0; qt < 4; ++qt)
    qf[qt] = *(const short8*)(Qb + (size_t)(q0w + qt * 16 + c) * D + head * HD + g * 8);

  const unsigned short* ksrc = Kb  + (size_t)(key0 + t / 4) * D + head * HD + (t % 4) * 8;
  const unsigned short* vsrc = Vtb + (size_t)(head * HD + t / 4) * N + key0 + (t % 4) * 8;
  const int sdst = (t / 4) * 40 + (t % 4) * 8;

  {
    const float4 gk = *(const float4*)ksrc;
    const float4 gv = *(const float4*)vsrc;
    *(float4*)&Ksh[0][sdst] = gk;
    *(float4*)&Vsh[0][sdst] = gv;
  }
  __syncthreads();

  floatx4 accL[4], accH[4];
  float ssum[4];
  #pragma unroll
  for (int qt = 0; qt < 4; ++qt) {
    accL[qt] = (floatx4){0.f, 0.f, 0.f, 0.f};
    accH[qt] = (floatx4){0.f, 0.f, 0.f, 0.f};
    ssum[qt] = 0.f;
  }

  const int NCH = SEG / 32;
  for (int ch = 0; ch < NCH; ++ch) {
    float4 gk, gv;
    const bool more = (ch + 1 < NCH);
    if (more) {
      gk = *(const float4*)(ksrc + (size_t)(ch + 1) * 32 * D);
      gv = *(const float4*)(vsrc + (ch + 1) * 32);
    }
    const unsigned short* kb = Ksh[ch & 1];
    const unsigned short* vb = Vsh[ch & 1];

    #pragma unroll
    for (int kk = 0; kk < 2; ++kk) {
      const short8 kf  = *(const short8*)&kb[(kk * 16 + c) * 40 + g * 8];
      const bf16x4 vf0 = *(const bf16x4*)&vb[c * 40 + kk * 16 + g * 4];
      const bf16x4 vf1 = *(const bf16x4*)&vb[(16 + c) * 40 + kk * 16 + g * 4];
      #pragma unroll
      for (int qt = 0; qt < 4; ++qt) {
        const floatx4 z = {0.f, 0.f, 0.f, 0.f};
        floatx4 sA = __builtin_amdgcn_mfma_f32_16x16x32_bf16(kf, qf[qt], z, 0, 0, 0);
        const float p0 = __expf(sA[0]);
        const float p1 = __expf(sA[1]);
        const float p2 = __expf(sA[2]);
        const float p3 = __expf(sA[3]);
        ssum[qt] += (p0 + p1) + (p2 + p3);
        union { unsigned u[2]; bf16x4 s; } pB;
        pB.u[0] = pack2bf(p0, p1);
        pB.u[1] = pack2bf(p2, p3);
        accL[qt] = __builtin_amdgcn_mfma_f32_16x16x16bf16_1k(vf0, pB.s, accL[qt], 0, 0, 0);
        accH[qt] = __builtin_amdgcn_mfma_f32_16x16x16bf16_1k(vf1, pB.s, accH[qt], 0, 0, 0);
      }
    }
    if (more) {
      *(float4*)&Ksh[(ch + 1) & 1][sdst] = gk;
      *(float4*)&Vsh[(ch + 1) & 1][sdst] = gv;
    }
    __syncthreads();
  }

  #pragma unroll
  for (int qt = 0; qt < 4; ++qt) {
    float s = ssum[qt];
    s += __shfl_xor(s, 16);
    s += __shfl_xor(s, 32);
    const size_t row = (size_t)(seg * NH + head) * N + q0w + qt * 16 + c;
    *(float4*)(pacc + row * HD + g * 4) =
        make_float4(accL[qt][0], accL[qt][1], accL[qt][2], accL[qt][3]);
    *(float4*)(pacc + row * HD + 16 + g * 4) =
        make_float4(accH[qt][0], accH[qt][1], accH[qt][2], accH[qt][3]);
    if (g == 0) psum[row] = s;
  }
}

// ---------------- Combine key segments -> o (hi/lo bf16) ---------------------
__global__ __launch_bounds__(256) void combine_kernel(
    const float* __restrict__ pacc, const float* __restrict__ psum,
    unsigned short* __restrict__ oh, unsigned short* __restrict__ ol)
{
  const int n = blockIdx.x;
  const int t = threadIdx.x;
  const int h = t >> 5;
  const int d = t & 31;
  float num = 0.f, den = 0.f;
  #pragma unroll
  for (int sgi = 0; sgi < KS; ++sgi) {
    const size_t b = (size_t)(sgi * NH + h) * N + n;
    num += pacc[b * HD + d];
    den += psum[b];
  }
  const float v = num / den;
  const unsigned short hh = f2bf(v);
  const size_t idx = (size_t)n * D + t;
  oh[idx] = hh;
  ol[idx] = f2bf(v - bf2f(hh));
}

// ---------------- Out projection: split-bf16 MFMA GEMM -----------------------
// out[m][j] = sum_d o[m][d] ow[j][d] + ob[j]; fp32 output.
__global__ __launch_bounds__(256) void gemm_out_mfma(
    const unsigned short* __restrict__ oh, const unsigned short* __restrict__ ol,
    const unsigned short* __restrict__ Wh, const unsigned short* __restrict__ Wl,
    const float* __restrict__ bias, float* __restrict__ out)
{
  const int t = threadIdx.x;
  const int wv = t >> 6, lane = t & 63, g = lane >> 4, c = lane & 15;
  const int n0 = blockIdx.x * 128;
  const int m0 = blockIdx.y * 64;
  const int nw = n0 + wv * 32;

  floatx4 acc[4][2];
  #pragma unroll
  for (int mt = 0; mt < 4; ++mt)
    #pragma unroll
    for (int nt = 0; nt < 2; ++nt) acc[mt][nt] = (floatx4){0.f, 0.f, 0.f, 0.f};

  #pragma unroll
  for (int pass = 0; pass < 3; ++pass) {
    const unsigned short* Ap = (pass == 1) ? ol : oh;
    const unsigned short* Wp = (pass == 2) ? Wl : Wh;
    for (int kc = 0; kc < 256; kc += 32) {
      short8 af[4], bf[2];
      #pragma unroll
      for (int mt = 0; mt < 4; ++mt)
        af[mt] = *(const short8*)(Ap + (size_t)(m0 + mt * 16 + c) * 256 + kc + g * 8);
      #pragma unroll
      for (int nt = 0; nt < 2; ++nt)
        bf[nt] = *(const short8*)(Wp + (size_t)(nw + nt * 16 + c) * 256 + kc + g * 8);
      #pragma unroll
      for (int mt = 0; mt < 4; ++mt)
        #pragma unroll
        for (int nt = 0; nt < 2; ++nt)
          acc[mt][nt] = __builtin_amdgcn_mfma_f32_16x16x32_bf16(af[mt], bf[nt], acc[mt][nt], 0, 0, 0);
    }
  }

  #pragma unroll
  for (int mt = 0; mt < 4; ++mt) {
    #pragma unroll
    for (int nt = 0; nt < 2; ++nt) {
      const int j = nw + nt * 16 + c;
      const float bj = bias[j];
      #pragma unroll
      for (int r = 0; r < 4; ++r) {
        const int m = m0 + mt * 16 + 4 * g + r;
        out[(size_t)m * 256 + j] = acc[mt][nt][r] + bj;
      }
    }
  }
}

extern "C" void kernel_launch(void* const* d_in, const int* in_sizes, int n_in,
                              void* d_out, int out_size, void* d_ws, size_t ws_size,
                              hipStream_t stream)
{
  (void)in_sizes; (void)n_in; (void)out_size; (void)ws_size;
  const float* x1  = (const float*)d_in[0];
  const float* x2  = (const float*)d_in[1];
  const float* lng = (const float*)d_in[2];
  const float* lnb = (const float*)d_in[3];
  const float* ipw = (const float*)d_in[4];
  const float* ipb = (const float*)d_in[5];
  const float* ow  = (const float*)d_in[6];
  const float* ob  = (const float*)d_in[7];
  float* out = (float*)d_out;

  char* p = (char*)d_ws;
  float* pacc = (float*)p; p += (size_t)KS * NH * N * HD * 4;
  float* psum = (float*)p; p += (size_t)KS * NH * N * 4;
  unsigned short* Qb   = (unsigned short*)p; p += (size_t)N * D * 2;
  unsigned short* Kb   = (unsigned short*)p; p += (size_t)N * D * 2;
  unsigned short* Vtb  = (unsigned short*)p; p += (size_t)D * N * 2;
  unsigned short* x2b_full = (unsigned short*)p; p += (size_t)NGR * D * 2;
  unsigned short* x2t_full = (unsigned short*)p; p += (size_t)D * NGR * 2;
  unsigned short* x1h  = (unsigned short*)p; p += (size_t)N * D * 2;
  unsigned short* x1l  = (unsigned short*)p; p += (size_t)N * D * 2;
  unsigned short* wh   = (unsigned short*)p; p += (size_t)768 * 256 * 2;
  unsigned short* wl   = (unsigned short*)p; p += (size_t)768 * 256 * 2;
  unsigned short* owh  = (unsigned short*)p; p += (size_t)256 * 256 * 2;
  unsigned short* owl  = (unsigned short*)p; p += (size_t)256 * 256 * 2;
  unsigned short* x2fh = (unsigned short*)p; p += (size_t)N * D * 2;
  unsigned short* x2fl = (unsigned short*)p; p += (size_t)N * D * 2;
  unsigned short* oh   = (unsigned short*)p; p += (size_t)N * D * 2;
  unsigned short* ol   = (unsigned short*)p; p += (size_t)N * D * 2;
  const unsigned short* x2b = x2b_full + (size_t)8 * D;
  const unsigned short* x2t = x2t_full + 8;

  conv_hilo_kernel<<<(CV_X1 + CV_W + CV_OW) / 256, 256, 0, stream>>>(
      x1, ipw, ow, x1h, x1l, wh, wl, owh, owl);
  prep_kernel<<<dim3(NGR / 16, 16), 256, 0, stream>>>(x2, x2b_full, x2t_full);
  stage1_mfma_kernel<<<144, 512, 0, stream>>>(x2b, x2t, lng, lnb, x2fh, x2fl);
  gemm_qkv_mfma<<<dim3(6, 36), 256, 0, stream>>>(
      x2fh, x2fl, x1h, x1l, wh, wl, ipb, Qb, Kb, Vtb);
  attn_mfma_kernel<<<dim3(KS, N / 128, NH), 128, 0, stream>>>(Qb, Kb, Vtb, pacc, psum);
  combine_kernel<<<N, 256, 0, stream>>>(pacc, psum, oh, ol);
  gemm_out_mfma<<<dim3(2, 36), 256, 0, stream>>>(oh, ol, owh, owl, ob, out);
}